// Round 7
// baseline (135.454 us; speedup 1.0000x reference)
//
#include <hip/hip_runtime.h>
#include <math.h>

// ---------------------------------------------------------------------------
// LowRankLoss: rank(channel-mean(raw)) vs rank(channel-mean(rect)),
// margin-ranking loss, size-averaged.  Rank is scale/normalization-invariant,
// so we compute the rank of the channel-SUM matrix via Gaussian elimination
// with partial pivoting.
//
// R7 = R6 (best, 134.1us) with ONE change: 16 nontemporal loads in flight
// per thread (was 8) — A/B test of per-wave issue depth vs a hard read cap.
// ---------------------------------------------------------------------------

#define N_BATCH 128
#define C_CH    256
#define H_DIM   32
#define W_DIM   64
#define HW      (H_DIM * W_DIM)      // 2048 floats per channel row
#define HW4     (HW / 4)             // 512 float4 per channel row

typedef float floatx4 __attribute__((ext_vector_type(4)));

// K1: channel partial sum.  Block b = (plane, chunk) streams a CONTIGUOUS
// (C/CHUNKS)*8KB region: per iteration the 512 threads read 16 consecutive
// 8KB channel rows (16 nt loads in flight per thread); thread t owns float4
// slot t (no LDS, no intra-block reduce).
template <int CHUNKS>
__global__ __launch_bounds__(512) void channel_sum_kernel(
    const float* __restrict__ raw, const float* __restrict__ rect,
    float* __restrict__ part /* [2*128*CHUNKS][2048] floats */)
{
    const int CPR = C_CH / CHUNKS;       // channels per block
    int b     = blockIdx.x;
    int chunk = b % CHUNKS;
    int plane = b / CHUNKS;              // 0..255
    int input = plane >> 7;
    int n     = plane & 127;

    const float* src = input ? rect : raw;
    const floatx4* p = (const floatx4*)(src +
        ((size_t)n * C_CH + (size_t)chunk * CPR) * HW) + threadIdx.x;

    floatx4 acc0 = (floatx4)(0.0f), acc1 = (floatx4)(0.0f);
#pragma unroll 1
    for (int cb = 0; cb < CPR; cb += 16) {
        floatx4 x0  = __builtin_nontemporal_load(p + (cb +  0) * HW4);
        floatx4 x1  = __builtin_nontemporal_load(p + (cb +  1) * HW4);
        floatx4 x2  = __builtin_nontemporal_load(p + (cb +  2) * HW4);
        floatx4 x3  = __builtin_nontemporal_load(p + (cb +  3) * HW4);
        floatx4 x4  = __builtin_nontemporal_load(p + (cb +  4) * HW4);
        floatx4 x5  = __builtin_nontemporal_load(p + (cb +  5) * HW4);
        floatx4 x6  = __builtin_nontemporal_load(p + (cb +  6) * HW4);
        floatx4 x7  = __builtin_nontemporal_load(p + (cb +  7) * HW4);
        floatx4 x8  = __builtin_nontemporal_load(p + (cb +  8) * HW4);
        floatx4 x9  = __builtin_nontemporal_load(p + (cb +  9) * HW4);
        floatx4 x10 = __builtin_nontemporal_load(p + (cb + 10) * HW4);
        floatx4 x11 = __builtin_nontemporal_load(p + (cb + 11) * HW4);
        floatx4 x12 = __builtin_nontemporal_load(p + (cb + 12) * HW4);
        floatx4 x13 = __builtin_nontemporal_load(p + (cb + 13) * HW4);
        floatx4 x14 = __builtin_nontemporal_load(p + (cb + 14) * HW4);
        floatx4 x15 = __builtin_nontemporal_load(p + (cb + 15) * HW4);
        acc0 += ((x0 + x1) + (x2 + x3)) + ((x4 + x5) + (x6 + x7));
        acc1 += ((x8 + x9) + (x10 + x11)) + ((x12 + x13) + (x14 + x15));
    }
    floatx4 acc = acc0 + acc1;
    ((floatx4*)part)[(size_t)b * 512 + threadIdx.x] = acc;
}

// K2: rank of one 32x64 matrix per single-wave block.  Sums the CHUNKS
// partials inline on load, then register-resident GE with partial pivoting;
// lane t owns column t.  All register arrays statically indexed.
template <int CHUNKS>
__global__ __launch_bounds__(64) void rank_kernel(
    const float* __restrict__ part, float* __restrict__ ranks)
{
    int mat = blockIdx.x;               // 0..255
    int t   = threadIdx.x;              // 0..63 = column owner
    const float* base = part + (size_t)mat * CHUNKS * HW;

    float a[H_DIM];
#pragma unroll
    for (int i = 0; i < H_DIM; ++i) {
        float s = 0.0f;
#pragma unroll
        for (int k = 0; k < CHUNKS; ++k)
            s += base[k * HW + i * W_DIM + t];
        a[i] = s;
    }

    unsigned used = 0;                  // bitmask of consumed pivot rows
    int rank = 0;
    for (int c = 0; c < W_DIM; ++c) {
        // broadcast column c to all lanes (wave-uniform after this)
        float v[H_DIM];
#pragma unroll
        for (int i = 0; i < H_DIM; ++i) v[i] = __shfl(a[i], c);

        // pivot: argmax |v_i| over unused rows (uniform computation)
        float best = 0.0f; int p = -1;
#pragma unroll
        for (int i = 0; i < H_DIM; ++i) {
            float av = fabsf(v[i]);
            bool cand = (((used >> i) & 1u) == 0u) && (av > best);
            best = cand ? av : best;
            p    = cand ? i  : p;
        }
        if (p >= 0) {
            used |= (1u << p);
            ++rank;
            float ap = 0.0f, vp = 1.0f;
#pragma unroll
            for (int i = 0; i < H_DIM; ++i) {
                if (i == p) { ap = a[i]; vp = v[i]; }
            }
            float inv = 1.0f / vp;
#pragma unroll
            for (int i = 0; i < H_DIM; ++i) {
                if (((used >> i) & 1u) == 0u) a[i] -= (v[i] * inv) * ap;
            }
            if (rank == H_DIM) break;
        }
    }
    if (t == 0) ranks[mat] = (float)rank;
}

// K3: loss = sum_n max(0, -(rank1[n]-rank2[n])) / N   (y=1, margin=0)
__global__ __launch_bounds__(128) void loss_kernel(
    const float* __restrict__ ranks, float* __restrict__ out)
{
    __shared__ float red[128];
    int t = threadIdx.x;
    float r1 = ranks[t];              // raw
    float r2 = ranks[N_BATCH + t];    // rectified
    red[t] = fmaxf(0.0f, -(r1 - r2));
    __syncthreads();
    for (int s = 64; s > 0; s >>= 1) {
        if (t < s) red[t] += red[t + s];
        __syncthreads();
    }
    if (t == 0) out[0] = red[0] / (float)N_BATCH;
}

extern "C" void kernel_launch(void* const* d_in, const int* in_sizes, int n_in,
                              void* d_out, int out_size, void* d_ws, size_t ws_size,
                              hipStream_t stream)
{
    const float* raw  = (const float*)d_in[0];
    const float* rect = (const float*)d_in[1];
    float* out = (float*)d_out;
    float* part = (float*)d_ws;

    const size_t need4 = (size_t)2 * N_BATCH * 4 * HW * sizeof(float) + 1024;
    if (ws_size >= need4) {
        // 4 chunks of 64 channels: 1024 blocks, each streams 512KB contiguous
        float* ranks = part + (size_t)2 * N_BATCH * 4 * HW;
        channel_sum_kernel<4><<<2 * N_BATCH * 4, 512, 0, stream>>>(raw, rect, part);
        rank_kernel<4><<<2 * N_BATCH, 64, 0, stream>>>(part, ranks);
        loss_kernel<<<1, 128, 0, stream>>>(ranks, out);
    } else {
        // fallback: 256 blocks, each streams a full 2MB plane
        float* ranks = part + (size_t)2 * N_BATCH * HW;
        channel_sum_kernel<1><<<2 * N_BATCH, 512, 0, stream>>>(raw, rect, part);
        rank_kernel<1><<<2 * N_BATCH, 64, 0, stream>>>(part, ranks);
        loss_kernel<<<1, 128, 0, stream>>>(ranks, out);
    }
}

// Round 8
// 133.868 us; speedup vs baseline: 1.0119x; 1.0119x over previous
//
#include <hip/hip_runtime.h>
#include <math.h>

// ---------------------------------------------------------------------------
// LowRankLoss: rank(channel-mean(raw)) vs rank(channel-mean(rect)),
// margin-ranking loss, size-averaged.  Rank is scale/normalization-invariant,
// so we compute the rank of the channel-SUM matrix via Gaussian elimination
// with partial pivoting.
//
// R8 = R6 exactly (best measured: 134.1us).  R7's depth-16 A/B was flat,
// confirming the ~4.5 TB/s read-path cap; 8 nt loads in flight is optimal.
// ---------------------------------------------------------------------------

#define N_BATCH 128
#define C_CH    256
#define H_DIM   32
#define W_DIM   64
#define HW      (H_DIM * W_DIM)      // 2048 floats per channel row
#define HW4     (HW / 4)             // 512 float4 per channel row

typedef float floatx4 __attribute__((ext_vector_type(4)));

// K1: channel partial sum.  Block b = (plane, chunk): plane = (input,n),
// chunk = one of CHUNKS groups of C/CHUNKS channels.  The block streams a
// CONTIGUOUS (C/CHUNKS)*8KB region: per iteration the 512 threads read one
// 8KB channel row; thread t owns float4 slot t (no LDS, no intra-block
// reduce).  8 named nontemporal loads in flight per thread.
template <int CHUNKS>
__global__ __launch_bounds__(512) void channel_sum_kernel(
    const float* __restrict__ raw, const float* __restrict__ rect,
    float* __restrict__ part /* [2*128*CHUNKS][2048] floats */)
{
    const int CPR = C_CH / CHUNKS;       // channels per block
    int b     = blockIdx.x;
    int chunk = b % CHUNKS;
    int plane = b / CHUNKS;              // 0..255
    int input = plane >> 7;
    int n     = plane & 127;

    const float* src = input ? rect : raw;
    const floatx4* p = (const floatx4*)(src +
        ((size_t)n * C_CH + (size_t)chunk * CPR) * HW) + threadIdx.x;

    floatx4 acc = (floatx4)(0.0f);
#pragma unroll 1
    for (int cb = 0; cb < CPR; cb += 8) {
        floatx4 x0 = __builtin_nontemporal_load(p + (cb + 0) * HW4);
        floatx4 x1 = __builtin_nontemporal_load(p + (cb + 1) * HW4);
        floatx4 x2 = __builtin_nontemporal_load(p + (cb + 2) * HW4);
        floatx4 x3 = __builtin_nontemporal_load(p + (cb + 3) * HW4);
        floatx4 x4 = __builtin_nontemporal_load(p + (cb + 4) * HW4);
        floatx4 x5 = __builtin_nontemporal_load(p + (cb + 5) * HW4);
        floatx4 x6 = __builtin_nontemporal_load(p + (cb + 6) * HW4);
        floatx4 x7 = __builtin_nontemporal_load(p + (cb + 7) * HW4);
        acc += ((x0 + x1) + (x2 + x3)) + ((x4 + x5) + (x6 + x7));
    }
    ((floatx4*)part)[(size_t)b * 512 + threadIdx.x] = acc;
}

// K2: rank of one 32x64 matrix per single-wave block.  Sums the CHUNKS
// partials inline on load, then register-resident GE with partial pivoting;
// lane t owns column t.  All register arrays statically indexed.
template <int CHUNKS>
__global__ __launch_bounds__(64) void rank_kernel(
    const float* __restrict__ part, float* __restrict__ ranks)
{
    int mat = blockIdx.x;               // 0..255
    int t   = threadIdx.x;              // 0..63 = column owner
    const float* base = part + (size_t)mat * CHUNKS * HW;

    float a[H_DIM];
#pragma unroll
    for (int i = 0; i < H_DIM; ++i) {
        float s = 0.0f;
#pragma unroll
        for (int k = 0; k < CHUNKS; ++k)
            s += base[k * HW + i * W_DIM + t];
        a[i] = s;
    }

    unsigned used = 0;                  // bitmask of consumed pivot rows
    int rank = 0;
    for (int c = 0; c < W_DIM; ++c) {
        // broadcast column c to all lanes (wave-uniform after this)
        float v[H_DIM];
#pragma unroll
        for (int i = 0; i < H_DIM; ++i) v[i] = __shfl(a[i], c);

        // pivot: argmax |v_i| over unused rows (uniform computation)
        float best = 0.0f; int p = -1;
#pragma unroll
        for (int i = 0; i < H_DIM; ++i) {
            float av = fabsf(v[i]);
            bool cand = (((used >> i) & 1u) == 0u) && (av > best);
            best = cand ? av : best;
            p    = cand ? i  : p;
        }
        if (p >= 0) {
            used |= (1u << p);
            ++rank;
            float ap = 0.0f, vp = 1.0f;
#pragma unroll
            for (int i = 0; i < H_DIM; ++i) {
                if (i == p) { ap = a[i]; vp = v[i]; }
            }
            float inv = 1.0f / vp;
#pragma unroll
            for (int i = 0; i < H_DIM; ++i) {
                if (((used >> i) & 1u) == 0u) a[i] -= (v[i] * inv) * ap;
            }
            if (rank == H_DIM) break;
        }
    }
    if (t == 0) ranks[mat] = (float)rank;
}

// K3: loss = sum_n max(0, -(rank1[n]-rank2[n])) / N   (y=1, margin=0)
__global__ __launch_bounds__(128) void loss_kernel(
    const float* __restrict__ ranks, float* __restrict__ out)
{
    __shared__ float red[128];
    int t = threadIdx.x;
    float r1 = ranks[t];              // raw
    float r2 = ranks[N_BATCH + t];    // rectified
    red[t] = fmaxf(0.0f, -(r1 - r2));
    __syncthreads();
    for (int s = 64; s > 0; s >>= 1) {
        if (t < s) red[t] += red[t + s];
        __syncthreads();
    }
    if (t == 0) out[0] = red[0] / (float)N_BATCH;
}

extern "C" void kernel_launch(void* const* d_in, const int* in_sizes, int n_in,
                              void* d_out, int out_size, void* d_ws, size_t ws_size,
                              hipStream_t stream)
{
    const float* raw  = (const float*)d_in[0];
    const float* rect = (const float*)d_in[1];
    float* out = (float*)d_out;
    float* part = (float*)d_ws;

    const size_t need4 = (size_t)2 * N_BATCH * 4 * HW * sizeof(float) + 1024;
    if (ws_size >= need4) {
        // 4 chunks of 64 channels: 1024 blocks, each streams 512KB contiguous
        float* ranks = part + (size_t)2 * N_BATCH * 4 * HW;
        channel_sum_kernel<4><<<2 * N_BATCH * 4, 512, 0, stream>>>(raw, rect, part);
        rank_kernel<4><<<2 * N_BATCH, 64, 0, stream>>>(part, ranks);
        loss_kernel<<<1, 128, 0, stream>>>(ranks, out);
    } else {
        // fallback: 256 blocks, each streams a full 2MB plane
        float* ranks = part + (size_t)2 * N_BATCH * HW;
        channel_sum_kernel<1><<<2 * N_BATCH, 512, 0, stream>>>(raw, rect, part);
        rank_kernel<1><<<2 * N_BATCH, 64, 0, stream>>>(part, ranks);
        loss_kernel<<<1, 128, 0, stream>>>(ranks, out);
    }
}